// Round 2
// baseline (812.047 us; speedup 1.0000x reference)
//
#include <hip/hip_runtime.h>
#include <hip/hip_bf16.h>

typedef __bf16 bf16_t;
typedef __bf16 bf16x8 __attribute__((ext_vector_type(8)));
typedef float floatx4 __attribute__((ext_vector_type(4)));

#define NB 2
#define NT 2048
#define NC 1024
#define NH 16
#define HD 64
#define BT (NB*NT)

// ---------------- convert x: fp32 -> bf16 (row-major copy) ----------------
__global__ void k_cvt_x(const float* __restrict__ x, bf16_t* __restrict__ xb, int n){
  int i = (blockIdx.x*blockDim.x + threadIdx.x)*4;
  if (i >= n) return;
  float4 v = *(const float4*)(x+i);
  bf16_t o[4] = {(bf16_t)v.x,(bf16_t)v.y,(bf16_t)v.z,(bf16_t)v.w};
  *(uint2*)(xb+i) = *(const uint2*)o;
}

// ------- transpose-convert: in fp32 [K][N] -> out bf16 [N][K] (tiled) -------
__global__ void k_cvt_t(const float* __restrict__ in, bf16_t* __restrict__ out, int K, int N){
  __shared__ float tile[32][33];
  int tid = threadIdx.x;
  int kt = blockIdx.y*32, nt = blockIdx.x*32;
  int row = tid>>3, c4 = (tid&7)*4;
  float4 v = *(const float4*)(in + (size_t)(kt+row)*N + nt + c4);
  tile[row][c4+0]=v.x; tile[row][c4+1]=v.y; tile[row][c4+2]=v.z; tile[row][c4+3]=v.w;
  __syncthreads();
  bf16_t o[4];
  #pragma unroll
  for (int i=0;i<4;i++) o[i] = (bf16_t)tile[c4+i][row];
  *(uint2*)(out + (size_t)(nt+row)*K + kt + c4) = *(const uint2*)o;
}

// ---------------- bf16 MFMA GEMM: C[M][N] = A[M][K] * Bt[N][K]^T ----------------
// block tile 64(M) x 128(N), BK=32, 4 waves each computing 32x64
template<bool BIAS, bool OUTBF>
__global__ __launch_bounds__(256) void k_gemm(
    const bf16_t* __restrict__ A, const bf16_t* __restrict__ Bt,
    void* __restrict__ Cv, const float* __restrict__ bias, int M, int N, int K){
  __shared__ __align__(16) bf16_t As[64][32];
  __shared__ __align__(16) bf16_t Bs[128][32];
  int tid = threadIdx.x;
  int wave = tid>>6, lane = tid&63, quad = lane>>4, l15 = lane&15;
  int m0 = blockIdx.y*64, n0 = blockIdx.x*128;
  int wm = (wave>>1)*32, wn = (wave&1)*64;
  floatx4 acc[2][4];
  #pragma unroll
  for(int i=0;i<2;i++)
    #pragma unroll
    for(int j=0;j<4;j++) acc[i][j] = (floatx4){0.f,0.f,0.f,0.f};
  int arow = tid>>2, ac8 = (tid&3)*8;
  const bf16_t* Ag  = A  + (size_t)(m0+arow)*K + ac8;
  const bf16_t* Bg0 = Bt + (size_t)(n0+arow)*K + ac8;
  const bf16_t* Bg1 = Bt + (size_t)(n0+arow+64)*K + ac8;
  for (int k0=0;k0<K;k0+=32){
    *(bf16x8*)&As[arow][ac8]    = *(const bf16x8*)(Ag  + k0);
    *(bf16x8*)&Bs[arow][ac8]    = *(const bf16x8*)(Bg0 + k0);
    *(bf16x8*)&Bs[arow+64][ac8] = *(const bf16x8*)(Bg1 + k0);
    __syncthreads();
    bf16x8 af[2], bfr[4];
    #pragma unroll
    for(int mi=0;mi<2;mi++) af[mi]  = *(const bf16x8*)&As[wm+mi*16+l15][quad*8];
    #pragma unroll
    for(int ni=0;ni<4;ni++) bfr[ni] = *(const bf16x8*)&Bs[wn+ni*16+l15][quad*8];
    #pragma unroll
    for(int mi=0;mi<2;mi++)
      #pragma unroll
      for(int ni=0;ni<4;ni++)
        acc[mi][ni] = __builtin_amdgcn_mfma_f32_16x16x32_bf16(af[mi], bfr[ni], acc[mi][ni],0,0,0);
    __syncthreads();
  }
  #pragma unroll
  for(int ni=0;ni<4;ni++){
    int col = n0 + wn + ni*16 + l15;
    float bv = 0.f; if (BIAS) bv = bias[col];
    #pragma unroll
    for(int mi=0;mi<2;mi++){
      int rowb = m0 + wm + mi*16 + quad*4;
      #pragma unroll
      for(int r=0;r<4;r++){
        float v = acc[mi][ni][r] + bv;
        if (OUTBF) ((bf16_t*)Cv)[(size_t)(rowb+r)*N + col] = (bf16_t)v;
        else       ((float*)Cv)[(size_t)(rowb+r)*N + col]  = v;
      }
    }
  }
}

// ------- RoPE + head split: qkv bf16 [BT][3072] -> Q/K/V bf16 [B*H][T][64] -------
__global__ void k_rope(const bf16_t* __restrict__ qkv, bf16_t* __restrict__ Qb,
                       bf16_t* __restrict__ Kb, bf16_t* __restrict__ Vb){
  int p = blockIdx.x*blockDim.x + threadIdx.x;     // pair index, exact grid
  int r = p / 1536;
  int c = (p - r*1536)*2;
  int s = c >> 10, rem = c & 1023;
  int h = rem >> 6, d = rem & 63, j = d >> 1;
  int b = r >> 11, t = r & 2047;
  float x1 = (float)qkv[(size_t)r*3072 + c];
  float x2 = (float)qkv[(size_t)r*3072 + c + 1];
  float o1, o2;
  if (s < 2){
    // freq = 10000^{-(j mod 16)/16} = 2^{-(j mod 16) * log2(10000)/16}
    float freq = exp2f(-0.8304820237218406f * (float)(j & 15));
    float ang = (float)t * freq;
    float sn, cs;
    sincosf(ang, &sn, &cs);
    o1 = x1*cs - x2*sn;
    o2 = x2*cs + x1*sn;
  } else { o1 = x1; o2 = x2; }
  bf16_t* dst = (s==0) ? Qb : (s==1 ? Kb : Vb);
  bf16_t o[2] = {(bf16_t)o1, (bf16_t)o2};
  *(unsigned int*)(dst + (size_t)((b*NH + h)*NT + t)*HD + d) = *(const unsigned int*)o;
}

// ---------------- fused attention: S=QK^T, softmax (no-max trick), attn write, O=PV ----------------
// block: 4 waves, 64 q rows per block (16 per wave), one (b,h) per blockIdx.y
__global__ __launch_bounds__(256) void k_attn(
    const bf16_t* __restrict__ Qb, const bf16_t* __restrict__ Kb, const bf16_t* __restrict__ Vb,
    float* __restrict__ attn, bf16_t* __restrict__ Ob){
  __shared__ __align__(16) bf16_t Ks[32][72];     // 32 keys x 64 dims (+8 pad)
  __shared__ __align__(16) bf16_t Vt[64][40];     // transposed: 64 dims x 32 keys (+8 pad)
  __shared__ __align__(16) bf16_t Ps[4][16][40];  // per-wave P transpose buffer
  int tid = threadIdx.x;
  int wave = tid>>6, lane = tid&63, quad = lane>>4, l15 = lane&15;
  int qt = blockIdx.x, bh = blockIdx.y;
  int h = bh & (NH-1);
  float slope = exp2f(-0.5f*(float)(h+1));        // ALiBi slope for H=16
  int qbase = qt*64 + wave*16;
  const bf16_t* qrow = Qb + ((size_t)bh*NT + qbase + l15)*HD;
  bf16x8 qa0 = *(const bf16x8*)(qrow + quad*8);
  bf16x8 qa1 = *(const bf16x8*)(qrow + 32 + quad*8);
  int sr = tid>>3, sc8 = (tid&7)*8;               // staging: 32 rows x 64 cols
  const bf16_t* kbase = Kb + ((size_t)bh*NT + sr)*HD + sc8;
  const bf16_t* vbase = Vb + ((size_t)bh*NT + sr)*HD + sc8;
  const floatx4 z4 = {0.f,0.f,0.f,0.f};

  // ---- pass 1: row sums of e^s (diag score >= 0 guarantees stability) ----
  float lsum[4] = {0.f,0.f,0.f,0.f};
  for (int k0=0;k0<NT;k0+=32){
    *(bf16x8*)&Ks[sr][sc8] = *(const bf16x8*)(kbase + (size_t)k0*HD);
    __syncthreads();
    #pragma unroll
    for (int nt=0;nt<2;nt++){
      bf16x8 kb0 = *(const bf16x8*)&Ks[nt*16+l15][quad*8];
      bf16x8 kb1 = *(const bf16x8*)&Ks[nt*16+l15][32+quad*8];
      floatx4 sv = __builtin_amdgcn_mfma_f32_16x16x32_bf16(qa0, kb0, z4,0,0,0);
      sv = __builtin_amdgcn_mfma_f32_16x16x32_bf16(qa1, kb1, sv,0,0,0);
      int kpos = k0 + nt*16 + l15;
      #pragma unroll
      for (int r=0;r<4;r++){
        int qpos = qbase + quad*4 + r;
        float sc = sv[r]*0.125f - slope*fabsf((float)(qpos - kpos));
        lsum[r] += __expf(sc);
      }
    }
    __syncthreads();
  }
  #pragma unroll
  for (int r=0;r<4;r++){
    #pragma unroll
    for (int off=1;off<16;off<<=1) lsum[r] += __shfl_xor(lsum[r], off, 16);
  }
  float invl[4];
  #pragma unroll
  for (int r=0;r<4;r++) invl[r] = 1.f / lsum[r];

  // ---- pass 2: recompute S, write normalized attn, accumulate O = P V ----
  floatx4 oacc[4] = {z4,z4,z4,z4};
  float* attnrow = attn + (size_t)bh*NT*NT;
  for (int k0=0;k0<NT;k0+=32){
    *(bf16x8*)&Ks[sr][sc8] = *(const bf16x8*)(kbase + (size_t)k0*HD);
    bf16x8 vl = *(const bf16x8*)(vbase + (size_t)k0*HD);
    #pragma unroll
    for (int i=0;i<8;i++) Vt[sc8+i][sr] = vl[i];   // transpose into LDS
    __syncthreads();
    #pragma unroll
    for (int nt=0;nt<2;nt++){
      bf16x8 kb0 = *(const bf16x8*)&Ks[nt*16+l15][quad*8];
      bf16x8 kb1 = *(const bf16x8*)&Ks[nt*16+l15][32+quad*8];
      floatx4 sv = __builtin_amdgcn_mfma_f32_16x16x32_bf16(qa0, kb0, z4,0,0,0);
      sv = __builtin_amdgcn_mfma_f32_16x16x32_bf16(qa1, kb1, sv,0,0,0);
      int kpos = k0 + nt*16 + l15;
      #pragma unroll
      for (int r=0;r<4;r++){
        int qpos = qbase + quad*4 + r;
        float sc = sv[r]*0.125f - slope*fabsf((float)(qpos - kpos));
        float pv = __expf(sc) * invl[r];
        attnrow[(size_t)qpos*NT + kpos] = pv;           // normalized attn out
        Ps[wave][quad*4+r][nt*16+l15] = (bf16_t)pv;     // D-layout -> LDS
      }
    }
    __syncthreads();                                     // Ps visible
    bf16x8 pa = *(const bf16x8*)&Ps[wave][l15][quad*8];  // A-layout read
    #pragma unroll
    for (int dt=0;dt<4;dt++){
      bf16x8 vb = *(const bf16x8*)&Vt[dt*16+l15][quad*8];
      oacc[dt] = __builtin_amdgcn_mfma_f32_16x16x32_bf16(pa, vb, oacc[dt],0,0,0);
    }
    __syncthreads();                                     // done with Ks/Vt/Ps
  }
  int b = bh >> 4;
  #pragma unroll
  for (int dt=0;dt<4;dt++){
    #pragma unroll
    for (int r=0;r<4;r++){
      int t = qbase + quad*4 + r;
      Ob[(size_t)(b*NT + t)*NC + h*HD + dt*16 + l15] = (bf16_t)oacc[dt][r];
    }
  }
}

extern "C" void kernel_launch(void* const* d_in, const int* in_sizes, int n_in,
                              void* d_out, int out_size, void* d_ws, size_t ws_size,
                              hipStream_t stream){
  const float* x    = (const float*)d_in[0];
  const float* Wqkv = (const float*)d_in[1];
  const float* Wout = (const float*)d_in[2];
  const float* bout = (const float*)d_in[3];
  (void)in_sizes; (void)n_in; (void)out_size; (void)ws_size;

  char* ws = (char*)d_ws;
  size_t off = 0;
  auto alloc = [&](size_t elems)->bf16_t* {
    bf16_t* p = (bf16_t*)(ws + off);
    off += ((elems*sizeof(bf16_t) + 255)/256)*256;
    return p;
  };
  bf16_t* Xb   = alloc((size_t)BT*NC);        // x as bf16
  bf16_t* Wqt  = alloc((size_t)3*NC*NC);      // W_qkv^T bf16 [3072][1024]
  bf16_t* Wot  = alloc((size_t)NC*NC);        // W_out^T bf16 [1024][1024]
  bf16_t* QKVb = alloc((size_t)BT*3*NC);      // qkv bf16 [4096][3072]
  bf16_t* Qb   = alloc((size_t)NB*NH*NT*HD);  // post-RoPE, [b*h][t][d]
  bf16_t* Kb   = alloc((size_t)NB*NH*NT*HD);
  bf16_t* Vb   = alloc((size_t)NB*NH*NT*HD);
  bf16_t* Ob   = alloc((size_t)BT*NC);        // attention out, [b*t][h*d]

  k_cvt_x<<<(BT*NC/4)/256, 256, 0, stream>>>(x, Xb, BT*NC);
  k_cvt_t<<<dim3(3*NC/32, NC/32), 256, 0, stream>>>(Wqkv, Wqt, NC, 3*NC);
  k_cvt_t<<<dim3(NC/32,   NC/32), 256, 0, stream>>>(Wout, Wot, NC, NC);
  k_gemm<false,true><<<dim3(3*NC/128, BT/64), 256, 0, stream>>>(Xb, Wqt, (void*)QKVb, nullptr, BT, 3*NC, NC);
  k_rope<<<(BT*1536)/256, 256, 0, stream>>>(QKVb, Qb, Kb, Vb);
  float* attn = (float*)d_out + (size_t)BT*NC;
  k_attn<<<dim3(NT/64, NB*NH), 256, 0, stream>>>(Qb, Kb, Vb, attn, Ob);
  k_gemm<true,false><<<dim3(NC/128, BT/64), 256, 0, stream>>>(Ob, Wot, d_out, bout, BT, NC, NC);
}